// Round 3
// baseline (298.141 us; speedup 1.0000x reference)
//
#include <hip/hip_runtime.h>

typedef short bf16x8 __attribute__((ext_vector_type(8)));
typedef float f32x4 __attribute__((ext_vector_type(4)));

#define MFMA16(a, b, c) __builtin_amdgcn_mfma_f32_16x16x32_bf16(a, b, c, 0, 0, 0)

#define SC 0.18033688011112043f  // log2(e)/8

__device__ __forceinline__ unsigned short f2bf(float f) {
  union { float f; unsigned u; } v; v.f = f;
  unsigned r = v.u + 0x7FFFu + ((v.u >> 16) & 1u);
  return (unsigned short)(r >> 16);
}

// ------------- convert fp32 -> bf16, three tensors in one launch ---------------
__global__ void cvt3_kernel(const float* __restrict__ a, const float* __restrict__ b,
                            const float* __restrict__ c, unsigned short* __restrict__ da,
                            unsigned short* __restrict__ db, unsigned short* __restrict__ dc,
                            int n4) {
  const float* s = blockIdx.y == 0 ? a : (blockIdx.y == 1 ? b : c);
  unsigned short* d = blockIdx.y == 0 ? da : (blockIdx.y == 1 ? db : dc);
  int i = blockIdx.x * blockDim.x + threadIdx.x;
  int stride = gridDim.x * blockDim.x;
  for (; i < n4; i += stride) {
    float4 v = ((const float4*)s)[i];
    ushort4 o;
    o.x = f2bf(v.x); o.y = f2bf(v.y); o.z = f2bf(v.z); o.w = f2bf(v.w);
    ((ushort4*)d)[i] = o;
  }
}

// ------------- transpose-convert: [R][C] fp32 -> [C][R] bf16 (per z-matrix) -----
template<int NSRC>
__global__ void tcvt_kernel(const float* __restrict__ s0p, const float* __restrict__ s1p,
                            const float* __restrict__ s2p, unsigned short* __restrict__ d0p,
                            unsigned short* __restrict__ d1p, unsigned short* __restrict__ d2p,
                            int R, int C) {
  __shared__ float tile[64][65];
  int z = blockIdx.z, mat = 0, zz = z;
  if (NSRC == 3) { mat = z >> 4; zz = z & 15; }
  const float* s = (mat == 0 ? s0p : (mat == 1 ? s1p : s2p)) + (size_t)zz * R * C;
  unsigned short* d = (mat == 0 ? d0p : (mat == 1 ? d1p : d2p)) + (size_t)zz * R * C;
  int r0 = blockIdx.x << 6, c0 = blockIdx.y << 6;
  int t = threadIdx.x;
  int lr = t >> 2, lc = (t & 3) << 4;
#pragma unroll
  for (int j = 0; j < 16; j += 4) {
    float4 v = *(const float4*)(s + (size_t)(r0 + lr) * C + c0 + lc + j);
    tile[lr][lc + j + 0] = v.x; tile[lr][lc + j + 1] = v.y;
    tile[lr][lc + j + 2] = v.z; tile[lr][lc + j + 3] = v.w;
  }
  __syncthreads();
  int oc = t >> 2, orr = (t & 3) << 4;
  unsigned short* dp = d + (size_t)(c0 + oc) * R + r0 + orr;
#pragma unroll
  for (int jj = 0; jj < 4; ++jj) {
    ushort4 o;
    o.x = f2bf(tile[orr + (jj << 2) + 0][oc]);
    o.y = f2bf(tile[orr + (jj << 2) + 1][oc]);
    o.z = f2bf(tile[orr + (jj << 2) + 2][oc]);
    o.w = f2bf(tile[orr + (jj << 2) + 3][oc]);
    *(ushort4*)(dp + (jj << 2)) = o;
  }
}

// ---------------- bf16 MFMA GEMM: C[8192][1024] = A[8192][1024] * W[1024][1024]^T + bias
// W is stored [n][k] (k-contiguous). MODE 0: bf16 out [b][h][s][64], scaled by `scale`
// MODE 1: bf16 out transposed [b][h][dv][2048] (for V). MODE 2: fp32 out [M][1024].
template<int MODE>
__global__ void gemm_kernel(const unsigned short* __restrict__ A,
                            const unsigned short* __restrict__ W,
                            const float* __restrict__ bias,
                            void* __restrict__ dstv, float scale) {
  __shared__ unsigned short lds[16384];
  unsigned short* lds_a = lds;
  unsigned short* lds_b = lds + 8192;
  const int tid = threadIdx.x;
  const int w = tid >> 6, l = tid & 63;
  const int g = l >> 4, x = l & 15;
  const int wm = (w >> 1) << 6, wn = (w & 1) << 6;
  // XCD-aware swizzle: XCD k owns m-tiles [8k, 8k+8), all n-tiles (W+A stripe ~4MB = L2)
  const int bid = blockIdx.x;
  const int xcd = bid & 7, slot = bid >> 3;
  const int m0 = ((xcd << 3) + (slot & 7)) << 7;
  const int n0 = (slot >> 3) << 7;
  const int lr = l & 7, lc = l >> 3;
  f32x4 acc[4][4] = {};
  for (int k0 = 0; k0 < 1024; k0 += 64) {
    __syncthreads();
#pragma unroll
    for (int p = 0; p < 4; ++p) {
      int r = (w << 5) + (p << 3) + lr;
      uint4 av = *(const uint4*)(A + ((size_t)(m0 + r) << 10) + k0 + (lc << 3));
      *(uint4*)((char*)lds_a + r * 128 + (((lc ^ lr) & 7) << 4)) = av;
      uint4 wv = *(const uint4*)(W + ((size_t)(n0 + r) << 10) + k0 + (lc << 3));
      *(uint4*)((char*)lds_b + r * 128 + (((lc ^ lr) & 7) << 4)) = wv;
    }
    __syncthreads();
#pragma unroll
    for (int kk = 0; kk < 2; ++kk) {
      bf16x8 af[4], bfr[4];
#pragma unroll
      for (int i = 0; i < 4; ++i) {
        int m = wm + (i << 4) + x;
        af[i] = *(const bf16x8*)((const char*)lds_a + m * 128 +
                                 (((kk << 6) + (g << 4)) ^ ((m & 7) << 4)));
        int n = wn + (i << 4) + x;
        bfr[i] = *(const bf16x8*)((const char*)lds_b + n * 128 +
                                  (((kk << 6) + (g << 4)) ^ ((n & 7) << 4)));
      }
#pragma unroll
      for (int i = 0; i < 4; ++i)
#pragma unroll
        for (int j = 0; j < 4; ++j)
          acc[i][j] = MFMA16(af[i], bfr[j], acc[i][j]);
    }
  }

  if (MODE == 0) {
    unsigned short* dst = (unsigned short*)dstv;
#pragma unroll
    for (int j = 0; j < 4; ++j) {
      int n = n0 + wn + (j << 4) + x;
      float bv = bias[n];
      int h = n >> 6, dd = n & 63;
#pragma unroll
      for (int i = 0; i < 4; ++i) {
#pragma unroll
        for (int r = 0; r < 4; ++r) {
          int M = m0 + wm + (i << 4) + (g << 2) + r;
          int b = M >> 11, s = M & 2047;
          dst[(size_t)(b * 16 + h) * 131072 + (size_t)s * 64 + dd] =
              f2bf((acc[i][j][r] + bv) * scale);
        }
      }
    }
  } else if (MODE == 2) {
    float* dst = (float*)dstv;
#pragma unroll
    for (int j = 0; j < 4; ++j) {
      int n = n0 + wn + (j << 4) + x;
      float bv = bias[n];
#pragma unroll
      for (int i = 0; i < 4; ++i) {
#pragma unroll
        for (int r = 0; r < 4; ++r) {
          int M = m0 + wm + (i << 4) + (g << 2) + r;
          dst[(size_t)M * 1024 + n] = acc[i][j][r] + bv;
        }
      }
    }
  } else {
    // MODE 1: V output transposed to [b][h][dv][2048] via LDS transpose
    __syncthreads();
#pragma unroll
    for (int i = 0; i < 4; ++i)
#pragma unroll
      for (int j = 0; j < 4; ++j) {
        int nl = wn + (j << 4) + x;
        float bv = bias[n0 + nl];
        ushort4 pk;
        pk.x = f2bf(acc[i][j][0] + bv);
        pk.y = f2bf(acc[i][j][1] + bv);
        pk.z = f2bf(acc[i][j][2] + bv);
        pk.w = f2bf(acc[i][j][3] + bv);
        int ml = wm + (i << 4) + (g << 2);
        *(ushort4*)((char*)lds + nl * 256 + ((ml * 2) ^ ((nl & 7) << 4))) = pk;
      }
    __syncthreads();
    unsigned short* dst = (unsigned short*)dstv;
    int nl = tid >> 1, half = tid & 1;
    int n = n0 + nl, h = n >> 6, dd = n & 63;
    int bb = m0 >> 11;
    size_t base = ((size_t)(bb * 16 + h) * 64 + dd) * 2048 + (m0 & 2047) + (half << 6);
#pragma unroll
    for (int c = 0; c < 8; ++c) {
      int mb = (half << 7) + (c << 4);
      uint4 vv = *(const uint4*)((char*)lds + nl * 256 + (mb ^ ((nl & 7) << 4)));
      *(uint4*)(dst + base + (c << 3)) = vv;
    }
  }
}

// ---- softmax + pack + permlane redistribution into PV A-fragments (T12) --------
// Input: s[tt] = S^T C-frag (lane (g,x) holds P-row x, t-col 16tt+4g+r), pre-scaled.
// Output: pa[kk][w] = A-frag words for PV (lane (g,x) needs P[x][32kk+8g+2w..+1]).
__device__ __forceinline__ void softmax_pack(const f32x4* s, f32x4& lsum,
                                             unsigned pa[2][4]) {
  unsigned pk[4][2];
#pragma unroll
  for (int tt = 0; tt < 4; ++tt) {
    float p0 = exp2f(s[tt][0]);
    float p1 = exp2f(s[tt][1]);
    float p2 = exp2f(s[tt][2]);
    float p3 = exp2f(s[tt][3]);
    lsum[0] += p0; lsum[1] += p1; lsum[2] += p2; lsum[3] += p3;
    asm("v_cvt_pk_bf16_f32 %0, %1, %2" : "=v"(pk[tt][0]) : "v"(p0), "v"(p1));
    asm("v_cvt_pk_bf16_f32 %0, %1, %2" : "=v"(pk[tt][1]) : "v"(p2), "v"(p3));
  }
#pragma unroll
  for (int kk = 0; kk < 2; ++kk)
#pragma unroll
    for (int p = 0; p < 2; ++p) {
      unsigned X = pk[2 * kk][p], Y = pk[2 * kk + 1][p];
      asm("v_permlane32_swap_b32 %0, %1" : "+v"(X), "+v"(Y));
      asm("v_permlane16_swap_b32 %0, %1" : "+v"(X), "+v"(Y));
      pa[kk][p] = X;
      pa[kk][2 + p] = Y;
    }
}

// ------------- flash attention: 4 waves x 64 q-rows, KV tile 64, dbuf LDS -------
// q (pre-scaled by SC), k: [b*16+h][2048][64] bf16 ; vT: [b*16+h][64][2048] bf16
// out: [b][s][1024] bf16
__global__ __launch_bounds__(256, 2)
void flash_kernel(const unsigned short* __restrict__ qb,
                  const unsigned short* __restrict__ kb,
                  const unsigned short* __restrict__ vtb,
                  unsigned short* __restrict__ out) {
  __shared__ unsigned short lds_k[2][4096];    // [t][d] swizzled
  __shared__ unsigned short lds_v[2][4096];    // [dv][t] swizzled
  const int tid = threadIdx.x, w = tid >> 6, l = tid & 63;
  const int g = l >> 4, x = l & 15;
  // XCD-aware swizzle: XCD k owns bh in [8k, 8k+8) -> K/V set ~4MB = L2
  const int bid = blockIdx.x;
  const int xcd = bid & 7, slot = bid >> 3;
  const int bh = (xcd << 3) + (slot >> 3);
  const int s0 = (slot & 7) << 8;
  const size_t boff = (size_t)bh << 17;
  const int lr = l & 7, lc = l >> 3;
  // q fragments: 4 x 16 rows, held in registers for the whole kernel
  bf16x8 qf0[4], qf1[4];
#pragma unroll
  for (int i = 0; i < 4; ++i) {
    const unsigned short* qp = qb + boff + ((size_t)(s0 + (w << 6) + (i << 4) + x) << 6);
    qf0[i] = *(const bf16x8*)(qp + (g << 3));
    qf1[i] = *(const bf16x8*)(qp + 32 + (g << 3));
  }
  f32x4 acc[4][4] = {};
  f32x4 lsum[4] = {};
  const int tr0 = (w << 3) + lr, tr1 = tr0 + 32;
  const int swst = ((lc ^ lr) & 7) << 4;
  uint4 kv0, kv1, vv0, vv1;
  // prologue: load + write tile 0
  {
    kv0 = *(const uint4*)(kb + boff + ((size_t)tr0 << 6) + (lc << 3));
    kv1 = *(const uint4*)(kb + boff + ((size_t)tr1 << 6) + (lc << 3));
    vv0 = *(const uint4*)(vtb + boff + ((size_t)tr0 << 11) + (lc << 3));
    vv1 = *(const uint4*)(vtb + boff + ((size_t)tr1 << 11) + (lc << 3));
    *(uint4*)((char*)lds_k[0] + tr0 * 128 + swst) = kv0;
    *(uint4*)((char*)lds_k[0] + tr1 * 128 + swst) = kv1;
    *(uint4*)((char*)lds_v[0] + tr0 * 128 + swst) = vv0;
    *(uint4*)((char*)lds_v[0] + tr1 * 128 + swst) = vv1;
  }
  __syncthreads();
  int cur = 0;
  for (int t0 = 0; t0 < 2048; t0 += 64) {
    const bool more = (t0 + 64) < 2048;
    // ---- QK^T phase: K-fragments register-cached, shared by all 4 q-frags ----
    bf16x8 kf0[4], kf1[4];
#pragma unroll
    for (int tt = 0; tt < 4; ++tt) {
      int trow = (tt << 4) + x;
      const char* kr = (const char*)lds_k[cur] + trow * 128;
      int sw = (trow & 7) << 4;
      kf0[tt] = *(const bf16x8*)(kr + ((g << 4) ^ sw));
      kf1[tt] = *(const bf16x8*)(kr + ((64 + (g << 4)) ^ sw));
    }
    unsigned pa[4][2][4];
#pragma unroll
    for (int i = 0; i < 4; ++i) {
      f32x4 s[4];
#pragma unroll
      for (int tt = 0; tt < 4; ++tt) {
        f32x4 t4 = {};
        t4 = MFMA16(kf0[tt], qf0[i], t4);
        t4 = MFMA16(kf1[tt], qf1[i], t4);
        s[tt] = t4;
      }
      softmax_pack(s, lsum[i], pa[i]);
    }
    // ---- issue next tile's global loads (T14: hide latency under PV) ----
    if (more) {
      int tn = t0 + 64;
      kv0 = *(const uint4*)(kb + boff + ((size_t)(tn + tr0) << 6) + (lc << 3));
      kv1 = *(const uint4*)(kb + boff + ((size_t)(tn + tr1) << 6) + (lc << 3));
      vv0 = *(const uint4*)(vtb + boff + ((size_t)tr0 << 11) + tn + (lc << 3));
      vv1 = *(const uint4*)(vtb + boff + ((size_t)tr1 << 11) + tn + (lc << 3));
    }
    // ---- PV phase: V-fragments read once, used by all 4 q-frags ----
#pragma unroll
    for (int kk = 0; kk < 2; ++kk)
#pragma unroll
      for (int nn = 0; nn < 4; ++nn) {
        int dv = (nn << 4) + x;
        bf16x8 vb = *(const bf16x8*)((const char*)lds_v[cur] + dv * 128 +
                                     (((kk << 6) + (g << 4)) ^ ((dv & 7) << 4)));
#pragma unroll
        for (int i = 0; i < 4; ++i) {
          union { unsigned u[4]; bf16x8 v; } ua;
          ua.u[0] = pa[i][kk][0]; ua.u[1] = pa[i][kk][1];
          ua.u[2] = pa[i][kk][2]; ua.u[3] = pa[i][kk][3];
          acc[i][nn] = MFMA16(ua.v, vb, acc[i][nn]);
        }
      }
    // ---- write next tile into the other buffer ----
    if (more) {
      int nb = cur ^ 1;
      *(uint4*)((char*)lds_k[nb] + tr0 * 128 + swst) = kv0;
      *(uint4*)((char*)lds_k[nb] + tr1 * 128 + swst) = kv1;
      *(uint4*)((char*)lds_v[nb] + tr0 * 128 + swst) = vv0;
      *(uint4*)((char*)lds_v[nb] + tr1 * 128 + swst) = vv1;
    }
    __syncthreads();
    cur ^= 1;
  }
  const int b = bh >> 4, h = bh & 15;
#pragma unroll
  for (int i = 0; i < 4; ++i) {
    float lt = (lsum[i][0] + lsum[i][1]) + (lsum[i][2] + lsum[i][3]);
    lt += __shfl_xor(lt, 16);
    lt += __shfl_xor(lt, 32);
    float inv = 1.f / lt;
    float iv[4];
#pragma unroll
    for (int r = 0; r < 4; ++r) iv[r] = __shfl(inv, (g << 2) + r);
    const int srow = s0 + (w << 6) + (i << 4) + (g << 2);
#pragma unroll
    for (int nn = 0; nn < 4; ++nn) {
      int dv = (nn << 4) + x;
      size_t base = ((size_t)(b * 2048 + srow)) * 1024 + (h << 6) + dv;
      out[base]        = f2bf(acc[i][nn][0] * iv[0]);
      out[base + 1024] = f2bf(acc[i][nn][1] * iv[1]);
      out[base + 2048] = f2bf(acc[i][nn][2] * iv[2]);
      out[base + 3072] = f2bf(acc[i][nn][3] * iv[3]);
    }
  }
}

// -------------------------------- launch ---------------------------------------
extern "C" void kernel_launch(void* const* d_in, const int* in_sizes, int n_in,
                              void* d_out, int out_size, void* d_ws, size_t ws_size,
                              hipStream_t stream) {
  const float* Q  = (const float*)d_in[0];
  const float* K  = (const float*)d_in[1];
  const float* V  = (const float*)d_in[2];
  const float* Wq = (const float*)d_in[3];
  const float* bq = (const float*)d_in[4];
  const float* Wk = (const float*)d_in[5];
  const float* bk = (const float*)d_in[6];
  const float* Wv = (const float*)d_in[7];
  const float* bv = (const float*)d_in[8];
  const float* Wo = (const float*)d_in[9];
  const float* bo = (const float*)d_in[10];

  if (ws_size < 109051904u) return;  // need ~104 MiB of scratch

  char* ws = (char*)d_ws;
  unsigned short* Qb    = (unsigned short*)(ws + 0);
  unsigned short* Kb    = (unsigned short*)(ws + 16777216);
  unsigned short* Vb    = (unsigned short*)(ws + 33554432);
  unsigned short* Wtq   = (unsigned short*)(ws + 50331648);
  unsigned short* Wtk   = (unsigned short*)(ws + 52428800);
  unsigned short* Wtv   = (unsigned short*)(ws + 54525952);
  unsigned short* Wot   = (unsigned short*)(ws + 56623104);
  unsigned short* qbuf  = (unsigned short*)(ws + 58720256);
  unsigned short* kbuf  = (unsigned short*)(ws + 75497472);
  unsigned short* vtbuf = (unsigned short*)(ws + 92274688);
  unsigned short* concat = Qb;  // alias: Qb dead after projection GEMMs

  cvt3_kernel<<<dim3(1024, 3), 256, 0, stream>>>(Q, K, V, Qb, Kb, Vb, 2097152);
  tcvt_kernel<3><<<dim3(16, 1, 48), 256, 0, stream>>>(Wq, Wk, Wv, Wtq, Wtk, Wtv, 1024, 64);
  tcvt_kernel<1><<<dim3(16, 16, 1), 256, 0, stream>>>(Wo, Wo, Wo, Wot, Wot, Wot, 1024, 1024);
  gemm_kernel<0><<<512, 256, 0, stream>>>(Qb, Wtq, bq, qbuf, SC);
  gemm_kernel<0><<<512, 256, 0, stream>>>(Kb, Wtk, bk, kbuf, 1.0f);
  gemm_kernel<1><<<512, 256, 0, stream>>>(Vb, Wtv, bv, vtbuf, 1.0f);
  flash_kernel<<<512, 256, 0, stream>>>(qbuf, kbuf, vtbuf, concat);
  gemm_kernel<2><<<512, 256, 0, stream>>>(concat, Wot, bo, (float*)d_out, 1.0f);
}